// Round 1
// baseline (621.326 us; speedup 1.0000x reference)
//
#include <hip/hip_runtime.h>
#include <stdint.h>

// ---------------------------------------------------------------------------
// ShiftedWindowAttention (Swin block): B=32, H=W=64, C=256, heads=8, hd=32,
// ws=8 (64 tok/window), shift=4.  2048 windows total.
// Pipeline: [cvt x/w to bf16] -> [bias+mask table] -> [QKV gemm (gathered)]
//           -> [per-window attention + out-proj fused]
// ---------------------------------------------------------------------------

typedef short short8 __attribute__((ext_vector_type(8)));
typedef short short4v __attribute__((ext_vector_type(4)));
typedef float f32x4 __attribute__((ext_vector_type(4)));

typedef __attribute__((address_space(1))) uint32_t g_u32;
typedef __attribute__((address_space(3))) uint32_t l_u32;

#define SCALE 0.17677669529663687f

__device__ __forceinline__ uint16_t f2bf(float f) {
  union { float f; uint32_t u; } c; c.f = f;
  uint32_t r = c.u + 0x7FFFu + ((c.u >> 16) & 1u);   // RNE
  return (uint16_t)(r >> 16);
}

__device__ __forceinline__ void g2lds16(const void* g, void* l) {
  // async global->LDS, 16B/lane, dest = lds base + lane*16
  __builtin_amdgcn_global_load_lds((const g_u32*)g, (l_u32*)l, 16, 0, 0);
}

// fp32 -> bf16 conversion, 8 elems/thread
__global__ __launch_bounds__(256) void cvt_kernel(const float* __restrict__ in,
                                                  uint16_t* __restrict__ out, int n) {
  int i = (blockIdx.x * 256 + threadIdx.x) * 8;
  if (i >= n) return;
  f32x4 a = *(const f32x4*)(in + i);
  f32x4 b = *(const f32x4*)(in + i + 4);
  short8 v;
  v[0] = (short)f2bf(a[0]); v[1] = (short)f2bf(a[1]);
  v[2] = (short)f2bf(a[2]); v[3] = (short)f2bf(a[3]);
  v[4] = (short)f2bf(b[0]); v[5] = (short)f2bf(b[1]);
  v[6] = (short)f2bf(b[2]); v[7] = (short)f2bf(b[3]);
  *(short8*)(out + i) = v;
}

// bias+mask table: bm[wd][head][i][j] = mask ? -1e30 : pos_enc[head][relidx(i,j)]
__global__ __launch_bounds__(256) void bias_kernel(const float* __restrict__ pe,
                                                   float* __restrict__ bm) {
  int bx = blockIdx.x;              // wd*8 + head
  int wd = bx >> 3, head = bx & 7;
  int hw = wd >> 3, ww = wd & 7;
  int tid = threadIdx.x;
  int i = tid >> 2;
  int jb = (tid & 3) * 16;
  int hi = hw * 8 + (i >> 3), xi = ww * 8 + (i & 7);
  int ri = (hi >= 60 ? 2 : (hi >= 56 ? 1 : 0)) * 3 + (xi >= 60 ? 2 : (xi >= 56 ? 1 : 0));
  for (int jj = 0; jj < 16; ++jj) {
    int j = jb + jj;
    int hj = hw * 8 + (j >> 3), xj = ww * 8 + (j & 7);
    int rj = (hj >= 60 ? 2 : (hj >= 56 ? 1 : 0)) * 3 + (xj >= 60 ? 2 : (xj >= 56 ? 1 : 0));
    float v;
    if (ri != rj) v = -1e30f;
    else v = pe[head * 225 + ((i >> 3) - (j >> 3) + 7) * 15 + (i & 7) - (j & 7) + 7];
    bm[(bx * 64 + i) * 64 + j] = v;
  }
}

// QKV projection: C[131072, 768] = Xgathered[131072,256] @ Wqkv^T + b
// 128x128 tile, BK=32, mfma 16x16x32 bf16, global_load_lds staging.
__global__ __launch_bounds__(256) void qkv_kernel(
    const uint16_t* __restrict__ xb, const uint16_t* __restrict__ wq,
    const float* __restrict__ bqkv,
    uint16_t* __restrict__ qws, uint16_t* __restrict__ kws, uint16_t* __restrict__ vws) {
  __shared__ uint16_t As[128 * 32];
  __shared__ uint16_t Bs[128 * 32];
  const int tid = threadIdx.x;
  const int lane = tid & 63;
  const int wv = tid >> 6;
  const int quad = lane >> 4;
  const int l15 = lane & 15;
  const int m0 = blockIdx.x * 128;
  const int n0 = blockIdx.y * 128;

  // staging: each wave stages 2 chunks (16 rows each) of A and B
  const uint16_t* aptr[2];
  const uint16_t* bptr[2];
  int chunkc[2];
  for (int j = 0; j < 2; ++j) {
    int c = wv * 2 + j;
    int row = c * 16 + (lane >> 2);
    int koff = (lane & 3) * 8;
    // gather: token -> rolled/windowed x row
    int token = m0 + row;
    int w = token >> 6, t = token & 63;
    int b = w >> 6, wd = w & 63;
    int h = (wd >> 3) * 8 + (t >> 3);
    int x = (wd & 7) * 8 + (t & 7);
    int src = b * 4096 + (((h + 4) & 63) << 6) + ((x + 4) & 63);
    aptr[j] = xb + src * 256 + koff;
    bptr[j] = wq + (n0 + row) * 256 + koff;
    chunkc[j] = c;
  }

  const int wm = (wv & 1) * 64;
  const int wn = (wv >> 1) * 64;
  f32x4 zero = {0.f, 0.f, 0.f, 0.f};
  f32x4 acc[4][4];
#pragma unroll
  for (int mi = 0; mi < 4; ++mi)
#pragma unroll
    for (int ni = 0; ni < 4; ++ni) acc[mi][ni] = zero;

  for (int ks = 0; ks < 8; ++ks) {
    int k0 = ks * 32;
#pragma unroll
    for (int j = 0; j < 2; ++j) {
      int c = chunkc[j];
      g2lds16(aptr[j] + k0, &As[c * 512]);
      g2lds16(bptr[j] + k0, &Bs[c * 512]);
    }
    __syncthreads();
    short8 af[4], bf[4];
#pragma unroll
    for (int mi = 0; mi < 4; ++mi)
      af[mi] = *(const short8*)&As[(wm + mi * 16 + l15) * 32 + quad * 8];
#pragma unroll
    for (int ni = 0; ni < 4; ++ni)
      bf[ni] = *(const short8*)&Bs[(wn + ni * 16 + l15) * 32 + quad * 8];
#pragma unroll
    for (int mi = 0; mi < 4; ++mi)
#pragma unroll
      for (int ni = 0; ni < 4; ++ni)
        acc[mi][ni] = __builtin_amdgcn_mfma_f32_16x16x32_bf16(af[mi], bf[ni], acc[mi][ni], 0, 0, 0);
    __syncthreads();
  }

  // epilogue: +bias, scatter to q/k ([w][h][t][d]) and v transposed ([w][h][d][t])
  float bq[4];
#pragma unroll
  for (int ni = 0; ni < 4; ++ni) bq[ni] = bqkv[n0 + wn + ni * 16 + l15];
#pragma unroll
  for (int mi = 0; mi < 4; ++mi) {
    int mbase = m0 + wm + mi * 16 + quad * 4;
    int w = mbase >> 6;          // same window for r=0..3 (quad*4+r <= 63)
    int t0 = mbase & 63;
#pragma unroll
    for (int ni = 0; ni < 4; ++ni) {
      int n = n0 + wn + ni * 16 + l15;
      int s = n >> 8, hd = (n >> 5) & 7, d = n & 31;
      if (s == 2) {
        short4v vv;
#pragma unroll
        for (int r = 0; r < 4; ++r) vv[r] = (short)f2bf(acc[mi][ni][r] + bq[ni]);
        *(short4v*)&vws[((w * 8 + hd) * 32 + d) * 64 + t0] = vv;
      } else {
        uint16_t* dst = (s == 0) ? qws : kws;
#pragma unroll
        for (int r = 0; r < 4; ++r)
          dst[((w * 8 + hd) * 64 + t0 + r) * 32 + d] = f2bf(acc[mi][ni][r] + bq[ni]);
      }
    }
  }
}

// XOR-swizzled LDS indexers (8-elem granules) — conflict-free b128 frag reads
__device__ __forceinline__ int p_idx(int row, int col) {
  return row * 64 + ((((col >> 3) ^ (row & 7)) << 3) | (col & 7));
}
__device__ __forceinline__ int ao_idx(int row, int col) {
  return row * 256 + ((((col >> 3) ^ (row & 7)) << 3) | (col & 7));
}

// Per-window: S=QK^T*scale+bias(masked), softmax, O=PV, then out-proj + scatter
__global__ __launch_bounds__(256) void attn_kernel(
    const uint16_t* __restrict__ qws, const uint16_t* __restrict__ kws,
    const uint16_t* __restrict__ vws, const uint16_t* __restrict__ wob,
    const float* __restrict__ bm, const float* __restrict__ bout,
    float* __restrict__ out) {
  __shared__ uint16_t P[4][64 * 64];    // per-wave P (softmax probs), swizzled
  __shared__ uint16_t AO[64 * 256];     // attention output (all heads), swizzled
  const int tid = threadIdx.x, lane = tid & 63, wv = tid >> 6;
  const int quad = lane >> 4, l15 = lane & 15;
  const int w = blockIdx.x;
  const int b = w >> 6, wd = w & 63;
  const int hw = wd >> 3, ww = wd & 7;
  f32x4 zero = {0.f, 0.f, 0.f, 0.f};

  for (int hh = 0; hh < 2; ++hh) {
    const int head = wv * 2 + hh;
    const uint16_t* qb = qws + (size_t)(w * 8 + head) * 2048;
    const uint16_t* kb = kws + (size_t)(w * 8 + head) * 2048;
    const uint16_t* vbase = vws + (size_t)(w * 8 + head) * 2048;
    const float* bmh = bm + (size_t)(wd * 8 + head) * 4096;

    short8 aq[4], bk[4];
#pragma unroll
    for (int mi = 0; mi < 4; ++mi)
      aq[mi] = *(const short8*)&qb[(mi * 16 + l15) * 32 + quad * 8];
#pragma unroll
    for (int ni = 0; ni < 4; ++ni)
      bk[ni] = *(const short8*)&kb[(ni * 16 + l15) * 32 + quad * 8];

    f32x4 s[4][4];
#pragma unroll
    for (int mi = 0; mi < 4; ++mi)
#pragma unroll
      for (int ni = 0; ni < 4; ++ni)
        s[mi][ni] = __builtin_amdgcn_mfma_f32_16x16x32_bf16(aq[mi], bk[ni], zero, 0, 0, 0);

    // scale + bias(+mask folded into bm table)
#pragma unroll
    for (int mi = 0; mi < 4; ++mi)
#pragma unroll
      for (int ni = 0; ni < 4; ++ni)
#pragma unroll
        for (int r = 0; r < 4; ++r) {
          int i = mi * 16 + quad * 4 + r, j = ni * 16 + l15;
          s[mi][ni][r] = s[mi][ni][r] * SCALE + bmh[i * 64 + j];
        }

    // row softmax: rows live on (mi,quad,r); cols on (ni, l15)
#pragma unroll
    for (int mi = 0; mi < 4; ++mi)
#pragma unroll
      for (int r = 0; r < 4; ++r) {
        float mx = fmaxf(fmaxf(s[mi][0][r], s[mi][1][r]), fmaxf(s[mi][2][r], s[mi][3][r]));
        for (int d = 1; d < 16; d <<= 1) mx = fmaxf(mx, __shfl_xor(mx, d, 64));
        float sm = 0.f;
#pragma unroll
        for (int ni = 0; ni < 4; ++ni) {
          float e = __expf(s[mi][ni][r] - mx);
          s[mi][ni][r] = e;
          sm += e;
        }
        for (int d = 1; d < 16; d <<= 1) sm += __shfl_xor(sm, d, 64);
        float inv = 1.f / sm;
#pragma unroll
        for (int ni = 0; ni < 4; ++ni) s[mi][ni][r] *= inv;
      }

    // P: C-layout -> LDS (swizzled) so we can re-read in A-layout
    uint16_t* Pw = P[wv];
#pragma unroll
    for (int mi = 0; mi < 4; ++mi)
#pragma unroll
      for (int ni = 0; ni < 4; ++ni)
#pragma unroll
        for (int r = 0; r < 4; ++r)
          Pw[p_idx(mi * 16 + quad * 4 + r, ni * 16 + l15)] = f2bf(s[mi][ni][r]);

    // O = P @ V  (V stored transposed [d][t] = B^T layout)
    f32x4 ov[4][2];
#pragma unroll
    for (int mi = 0; mi < 4; ++mi)
#pragma unroll
      for (int ni = 0; ni < 2; ++ni) ov[mi][ni] = zero;
#pragma unroll
    for (int ki = 0; ki < 2; ++ki) {
      short8 vf[2];
#pragma unroll
      for (int ni = 0; ni < 2; ++ni)
        vf[ni] = *(const short8*)&vbase[(ni * 16 + l15) * 64 + ki * 32 + quad * 8];
#pragma unroll
      for (int mi = 0; mi < 4; ++mi) {
        short8 pa = *(const short8*)&Pw[p_idx(mi * 16 + l15, (ki * 4 + quad) * 8)];
#pragma unroll
        for (int ni = 0; ni < 2; ++ni)
          ov[mi][ni] = __builtin_amdgcn_mfma_f32_16x16x32_bf16(pa, vf[ni], ov[mi][ni], 0, 0, 0);
      }
    }
#pragma unroll
    for (int mi = 0; mi < 4; ++mi)
#pragma unroll
      for (int ni = 0; ni < 2; ++ni)
#pragma unroll
        for (int r = 0; r < 4; ++r)
          AO[ao_idx(mi * 16 + quad * 4 + r, head * 32 + ni * 16 + l15)] = f2bf(ov[mi][ni][r]);
  }

  __syncthreads();

  // out-proj: C2[64,256] = AO @ Wout^T + bout, each wave owns 64 cols
  const int n0 = wv * 64;
  f32x4 o2[4][4];
#pragma unroll
  for (int mi = 0; mi < 4; ++mi)
#pragma unroll
    for (int ni = 0; ni < 4; ++ni) o2[mi][ni] = zero;
  for (int ks = 0; ks < 8; ++ks) {
    short8 am[4], wb[4];
#pragma unroll
    for (int mi = 0; mi < 4; ++mi)
      am[mi] = *(const short8*)&AO[ao_idx(mi * 16 + l15, ks * 32 + quad * 8)];
#pragma unroll
    for (int ni = 0; ni < 4; ++ni)
      wb[ni] = *(const short8*)&wob[(n0 + ni * 16 + l15) * 256 + ks * 32 + quad * 8];
#pragma unroll
    for (int mi = 0; mi < 4; ++mi)
#pragma unroll
      for (int ni = 0; ni < 4; ++ni)
        o2[mi][ni] = __builtin_amdgcn_mfma_f32_16x16x32_bf16(am[mi], wb[ni], o2[mi][ni], 0, 0, 0);
  }
  float bo[4];
#pragma unroll
  for (int ni = 0; ni < 4; ++ni) bo[ni] = bout[n0 + ni * 16 + l15];
#pragma unroll
  for (int mi = 0; mi < 4; ++mi)
#pragma unroll
    for (int r = 0; r < 4; ++r) {
      int t = mi * 16 + quad * 4 + r;
      int h = hw * 8 + (t >> 3), xx = ww * 8 + (t & 7);
      int row = (((h + 4) & 63) << 6) + ((xx + 4) & 63);   // merge + inverse roll
      float* op = out + ((size_t)b * 4096 + row) * 256 + n0;
#pragma unroll
      for (int ni = 0; ni < 4; ++ni) op[ni * 16 + l15] = o2[mi][ni][r] + bo[ni];
    }
}

extern "C" void kernel_launch(void* const* d_in, const int* in_sizes, int n_in,
                              void* d_out, int out_size, void* d_ws, size_t ws_size,
                              hipStream_t stream) {
  const float* x = (const float*)d_in[0];       // [32,4096,256]
  const float* w_qkv = (const float*)d_in[1];   // [768,256]
  const float* b_qkv = (const float*)d_in[2];   // [768]
  const float* w_out = (const float*)d_in[3];   // [256,256]
  const float* b_out = (const float*)d_in[4];   // [256]
  const float* pos_enc = (const float*)d_in[5]; // [8,225]
  float* out = (float*)d_out;

  uint8_t* ws = (uint8_t*)d_ws;
  uint16_t* xb  = (uint16_t*)(ws);                 // 67,108,864 B
  uint16_t* wqb = (uint16_t*)(ws + 67108864);      //    393,216 B
  uint16_t* wob = (uint16_t*)(ws + 67502080);      //    131,072 B
  float*    bmt = (float*)   (ws + 67633152);      //  8,388,608 B
  uint16_t* qws = (uint16_t*)(ws + 76021760);      // 67,108,864 B
  uint16_t* kws = (uint16_t*)(ws + 143130624);     // 67,108,864 B
  uint16_t* vws = (uint16_t*)(ws + 210239488);     // 67,108,864 B -> total 277,348,352 B

  cvt_kernel<<<16384, 256, 0, stream>>>(x, xb, 33554432);
  cvt_kernel<<<96, 256, 0, stream>>>(w_qkv, wqb, 196608);
  cvt_kernel<<<32, 256, 0, stream>>>(w_out, wob, 65536);
  bias_kernel<<<512, 256, 0, stream>>>(pos_enc, bmt);
  qkv_kernel<<<dim3(1024, 6), 256, 0, stream>>>(xb, wqb, b_qkv, qws, kws, vws);
  attn_kernel<<<2048, 256, 0, stream>>>(qws, kws, vws, wob, bmt, b_out, out);
}

// Round 2
// 440.659 us; speedup vs baseline: 1.4100x; 1.4100x over previous
//
#include <hip/hip_runtime.h>
#include <stdint.h>

// ---------------------------------------------------------------------------
// ShiftedWindowAttention: B=32, H=W=64, C=256, heads=8, hd=32, ws=8, shift=4.
// Pipeline:
//   cvtx (f32->bf16 + roll + window-partition row gather)
//   cvt  (weights f32->bf16)
//   bias (pos_enc -> transposed/interleaved bias+mask table, f32)
//   qkv  (GEMM 131072x768x256, LDS-transpose epilogue -> q[t][d], k[t][d], v[d][t])
//   attn (per-(window,head) wave: S^T=K*Q^T, column softmax, P LDS roundtrip,
//         O=P*V, AO[token][256] bf16)  -- no __syncthreads
//   oproj(GEMM 131072x256x256 + merge/inv-roll scatter, f32 out)
// ---------------------------------------------------------------------------

typedef short short8 __attribute__((ext_vector_type(8)));
typedef float f32x4 __attribute__((ext_vector_type(4)));

typedef __attribute__((address_space(1))) uint32_t g_u32;
typedef __attribute__((address_space(3))) uint32_t l_u32;

#define SCALE 0.17677669529663687f

__device__ __forceinline__ uint16_t f2bf(float f) {
  union { float f; uint32_t u; } c; c.f = f;
  uint32_t r = c.u + 0x7FFFu + ((c.u >> 16) & 1u);   // RNE
  return (uint16_t)(r >> 16);
}

__device__ __forceinline__ void g2lds16(const void* g, void* l) {
  __builtin_amdgcn_global_load_lds((const g_u32*)g, (l_u32*)l, 16, 0, 0);
}

// ---- x: f32 -> bf16, fused roll(-4,-4) + window partition (row permutation)
__global__ __launch_bounds__(256) void cvtx_kernel(const float* __restrict__ x,
                                                   uint16_t* __restrict__ xb) {
  int tid = threadIdx.x;
  int token = blockIdx.x * 8 + (tid >> 5);
  int c = (tid & 31) * 8;
  int w = token >> 6, t = token & 63;
  int b = w >> 6, wd = w & 63;
  int h = (wd >> 3) * 8 + (t >> 3);
  int xx = (wd & 7) * 8 + (t & 7);
  int src = b * 4096 + (((h + 4) & 63) << 6) + ((xx + 4) & 63);
  const float* sp = x + (size_t)src * 256 + c;
  f32x4 a = *(const f32x4*)sp;
  f32x4 d = *(const f32x4*)(sp + 4);
  short8 v;
  v[0] = (short)f2bf(a[0]); v[1] = (short)f2bf(a[1]);
  v[2] = (short)f2bf(a[2]); v[3] = (short)f2bf(a[3]);
  v[4] = (short)f2bf(d[0]); v[5] = (short)f2bf(d[1]);
  v[6] = (short)f2bf(d[2]); v[7] = (short)f2bf(d[3]);
  *(short8*)&xb[(size_t)token * 256 + c] = v;
}

// ---- plain f32 -> bf16 (weights)
__global__ __launch_bounds__(256) void cvt_kernel(const float* __restrict__ in,
                                                  uint16_t* __restrict__ out, int n) {
  int i = (blockIdx.x * 256 + threadIdx.x) * 8;
  if (i >= n) return;
  f32x4 a = *(const f32x4*)(in + i);
  f32x4 b = *(const f32x4*)(in + i + 4);
  short8 v;
  v[0] = (short)f2bf(a[0]); v[1] = (short)f2bf(a[1]);
  v[2] = (short)f2bf(a[2]); v[3] = (short)f2bf(a[3]);
  v[4] = (short)f2bf(b[0]); v[5] = (short)f2bf(b[1]);
  v[6] = (short)f2bf(b[2]); v[7] = (short)f2bf(b[3]);
  *(short8*)(out + i) = v;
}

// ---- bias+mask table, transposed+interleaved: bm[wd][head][kk][a(16)][ni(4)]
//      value = bias for (query i = ni*16+a, key j = kk); mask folded as -1e30
__global__ __launch_bounds__(256) void bias_kernel(const float* __restrict__ pe,
                                                   float* __restrict__ bm) {
  int bx = blockIdx.x;              // wd*8 + head
  int wd = bx >> 3, head = bx & 7;
  int hw = wd >> 3, ww = wd & 7;
  int tid = threadIdx.x;
  int kk = tid >> 2, a0 = (tid & 3) * 4;
  int jy = kk >> 3, jx = kk & 7;
  int hj = hw * 8 + jy, xj = ww * 8 + jx;
  int rj = (hj >= 60 ? 2 : (hj >= 56 ? 1 : 0)) * 3 + (xj >= 60 ? 2 : (xj >= 56 ? 1 : 0));
  float* dst = bm + (size_t)bx * 4096 + kk * 64 + a0 * 4;
  for (int aa = 0; aa < 4; ++aa) {
    int a = a0 + aa;
    f32x4 v;
#pragma unroll
    for (int ni = 0; ni < 4; ++ni) {
      int i = ni * 16 + a;
      int iy = i >> 3, ix = i & 7;
      int hi = hw * 8 + iy, xi = ww * 8 + ix;
      int ri = (hi >= 60 ? 2 : (hi >= 56 ? 1 : 0)) * 3 + (xi >= 60 ? 2 : (xi >= 56 ? 1 : 0));
      v[ni] = (ri != rj) ? -1e30f : pe[head * 225 + (iy - jy + 7) * 15 + (ix - jx + 7)];
    }
    *(f32x4*)(dst + aa * 4) = v;
  }
}

// ---- QKV projection GEMM: C[131072,768] = xb @ wq^T + b
//      outputs: q,k as [win][head][t][32], v transposed [win][head][32][t]
__global__ __launch_bounds__(256) void qkv_kernel(
    const uint16_t* __restrict__ xb, const uint16_t* __restrict__ wq,
    const float* __restrict__ bqkv,
    uint16_t* __restrict__ qws, uint16_t* __restrict__ kws, uint16_t* __restrict__ vws) {
  __shared__ uint16_t sm[16384];                 // 32 KB: staging 16 KB, epi 32 KB
  uint16_t* As = sm;                             // [128][32]
  uint16_t* Bs = sm + 4096;                      // [128][32]
  const int tid = threadIdx.x, lane = tid & 63, wv = tid >> 6;
  const int quad = lane >> 4, l15 = lane & 15;
  const int n0 = blockIdx.x * 128;               // n fastest -> A-tile L2 reuse
  const int m0 = blockIdx.y * 128;

  const int c0 = wv * 2, c1 = c0 + 1;
  const uint16_t* ap0 = xb + (size_t)(m0 + c0 * 16 + (lane >> 2)) * 256 + (lane & 3) * 8;
  const uint16_t* ap1 = xb + (size_t)(m0 + c1 * 16 + (lane >> 2)) * 256 + (lane & 3) * 8;
  const uint16_t* bp0 = wq + (size_t)(n0 + c0 * 16 + (lane >> 2)) * 256 + (lane & 3) * 8;
  const uint16_t* bp1 = wq + (size_t)(n0 + c1 * 16 + (lane >> 2)) * 256 + (lane & 3) * 8;

  const int wm = (wv & 1) * 64, wn = (wv >> 1) * 64;
  f32x4 zero = {0.f, 0.f, 0.f, 0.f};
  f32x4 acc[4][4];
#pragma unroll
  for (int mi = 0; mi < 4; ++mi)
#pragma unroll
    for (int ni = 0; ni < 4; ++ni) acc[mi][ni] = zero;

  for (int ks = 0; ks < 8; ++ks) {
    int k0 = ks * 32;
    g2lds16(ap0 + k0, &As[c0 * 512]);
    g2lds16(ap1 + k0, &As[c1 * 512]);
    g2lds16(bp0 + k0, &Bs[c0 * 512]);
    g2lds16(bp1 + k0, &Bs[c1 * 512]);
    __syncthreads();
    short8 af[4], bf[4];
#pragma unroll
    for (int mi = 0; mi < 4; ++mi)
      af[mi] = *(const short8*)&As[(wm + mi * 16 + l15) * 32 + quad * 8];
#pragma unroll
    for (int ni = 0; ni < 4; ++ni)
      bf[ni] = *(const short8*)&Bs[(wn + ni * 16 + l15) * 32 + quad * 8];
#pragma unroll
    for (int mi = 0; mi < 4; ++mi)
#pragma unroll
      for (int ni = 0; ni < 4; ++ni)
        acc[mi][ni] = __builtin_amdgcn_mfma_f32_16x16x32_bf16(af[mi], bf[ni], acc[mi][ni], 0, 0, 0);
    __syncthreads();
  }

  // ---- epilogue: bias add, LDS transpose (per-wave 8 KB), vectorized stores
  float bq4[4];
#pragma unroll
  for (int ni = 0; ni < 4; ++ni) bq4[ni] = bqkv[n0 + wn + ni * 16 + l15];
  const int ng0 = n0 + wn;                       // 64-aligned, single section
  const int sct = ng0 >> 8;                      // 0=q, 1=k, 2=v
  uint16_t* epi = sm + wv * 4096;

  if (sct < 2) {
    // layout [t][n] swizzled 16B granules
#pragma unroll
    for (int mi = 0; mi < 4; ++mi)
#pragma unroll
      for (int ni = 0; ni < 4; ++ni)
#pragma unroll
        for (int r = 0; r < 4; ++r) {
          int t = mi * 16 + quad * 4 + r, n = ni * 16 + l15;
          epi[t * 64 + ((((n >> 3) ^ (t & 7)) << 3) | (n & 7))] = f2bf(acc[mi][ni][r] + bq4[ni]);
        }
    uint16_t* dst = (sct == 0) ? qws : kws;
    const int tb = m0 + wm;
#pragma unroll
    for (int cc = 0; cc < 8; ++cc) {
      int chunk = cc * 64 + lane;
      int trow = chunk >> 3, part = chunk & 7;
      short8 v = *(const short8*)&epi[trow * 64 + ((part ^ (trow & 7)) << 3)];
      int tok = tb + trow, w = tok >> 6, t = tok & 63;
      int ng = ng0 + part * 8, hd = (ng >> 5) & 7, d = ng & 31;
      *(short8*)&dst[(size_t)((w * 8 + hd) * 64 + t) * 32 + d] = v;
    }
  } else {
    // v: layout [n(=d)][t] (transposed), swizzled
#pragma unroll
    for (int mi = 0; mi < 4; ++mi)
#pragma unroll
      for (int ni = 0; ni < 4; ++ni)
#pragma unroll
        for (int r = 0; r < 4; ++r) {
          int t = mi * 16 + quad * 4 + r, n = ni * 16 + l15;
          epi[n * 64 + ((((t >> 3) ^ (n & 7)) << 3) | (t & 7))] = f2bf(acc[mi][ni][r] + bq4[ni]);
        }
    const int tb = m0 + wm;
#pragma unroll
    for (int cc = 0; cc < 8; ++cc) {
      int chunk = cc * 64 + lane;
      int drow = chunk >> 3, part = chunk & 7;
      short8 v = *(const short8*)&epi[drow * 64 + ((part ^ (drow & 7)) << 3)];
      int ng = ng0 + drow, hd = (ng >> 5) & 7, d = ng & 31;
      int tok = tb + part * 8, w = tok >> 6, t = tok & 63;
      *(short8*)&vws[(size_t)((w * 8 + hd) * 32 + d) * 64 + t] = v;
    }
  }
}

// ---- attention: one wave per (window, head). S^T = K*Q^T, column softmax,
//      P via per-wave LDS, O = P*V, write AO[token][256] bf16. No barriers.
__global__ __launch_bounds__(256) void attn_kernel(
    const uint16_t* __restrict__ qws, const uint16_t* __restrict__ kws,
    const uint16_t* __restrict__ vws, const float* __restrict__ bm,
    uint16_t* __restrict__ ao) {
  __shared__ uint16_t P[4][4096];                // 8 KB per wave
  const int tid = threadIdx.x, lane = tid & 63, wv = tid >> 6;
  const int quad = lane >> 4, l15 = lane & 15;
  const int gid = blockIdx.x * 4 + wv;
  const int w = gid >> 3, head = gid & 7;
  const uint16_t* qb = qws + (size_t)(w * 8 + head) * 2048;
  const uint16_t* kb = kws + (size_t)(w * 8 + head) * 2048;
  const uint16_t* vb = vws + (size_t)(w * 8 + head) * 2048;
  const float* bmh = bm + (size_t)((w & 63) * 8 + head) * 4096;
  f32x4 zero = {0.f, 0.f, 0.f, 0.f};

  short8 ak[4], bq[4];
#pragma unroll
  for (int mi = 0; mi < 4; ++mi)
    ak[mi] = *(const short8*)&kb[(mi * 16 + l15) * 32 + quad * 8];
#pragma unroll
  for (int ni = 0; ni < 4; ++ni)
    bq[ni] = *(const short8*)&qb[(ni * 16 + l15) * 32 + quad * 8];

  f32x4 s[4][4];                                 // S^T: row kk, col q
#pragma unroll
  for (int mi = 0; mi < 4; ++mi)
#pragma unroll
    for (int ni = 0; ni < 4; ++ni)
      s[mi][ni] = __builtin_amdgcn_mfma_f32_16x16x32_bf16(ak[mi], bq[ni], zero, 0, 0, 0);

  // scale + bias (mask folded): coalesced f32x4 from interleaved table
#pragma unroll
  for (int mi = 0; mi < 4; ++mi)
#pragma unroll
    for (int r = 0; r < 4; ++r) {
      int kk = mi * 16 + quad * 4 + r;
      f32x4 b4 = *(const f32x4*)&bmh[kk * 64 + l15 * 4];
#pragma unroll
      for (int ni = 0; ni < 4; ++ni)
        s[mi][ni][r] = s[mi][ni][r] * SCALE + b4[ni];
    }

  // softmax per column q: 16 in-lane values + 2 shfls
#pragma unroll
  for (int ni = 0; ni < 4; ++ni) {
    float mx = s[0][ni][0];
#pragma unroll
    for (int mi = 0; mi < 4; ++mi)
#pragma unroll
      for (int r = 0; r < 4; ++r) mx = fmaxf(mx, s[mi][ni][r]);
    mx = fmaxf(mx, __shfl_xor(mx, 16, 64));
    mx = fmaxf(mx, __shfl_xor(mx, 32, 64));
    float sum = 0.f;
#pragma unroll
    for (int mi = 0; mi < 4; ++mi)
#pragma unroll
      for (int r = 0; r < 4; ++r) {
        float e = __expf(s[mi][ni][r] - mx);
        s[mi][ni][r] = e;
        sum += e;
      }
    sum += __shfl_xor(sum, 16, 64);
    sum += __shfl_xor(sum, 32, 64);
    float inv = 1.f / sum;
#pragma unroll
    for (int mi = 0; mi < 4; ++mi)
#pragma unroll
      for (int r = 0; r < 4; ++r) s[mi][ni][r] *= inv;
  }

  // P[q][kk] bf16, swizzled, packed-pair writes (intra-wave, no barrier)
  uint16_t* Pw = P[wv];
#pragma unroll
  for (int mi = 0; mi < 4; ++mi)
#pragma unroll
    for (int ni = 0; ni < 4; ++ni)
#pragma unroll
      for (int rp = 0; rp < 2; ++rp) {
        int kk = mi * 16 + quad * 4 + rp * 2;
        int q = ni * 16 + l15;
        uint32_t pk = (uint32_t)f2bf(s[mi][ni][rp * 2]) |
                      ((uint32_t)f2bf(s[mi][ni][rp * 2 + 1]) << 16);
        *(uint32_t*)&Pw[q * 64 + ((((kk >> 3) ^ (q & 7)) << 3) | (kk & 7))] = pk;
      }

  // O = P @ V (V stored [d][t] = B-operand layout)
  f32x4 o[4][2];
#pragma unroll
  for (int mi = 0; mi < 4; ++mi) { o[mi][0] = zero; o[mi][1] = zero; }
#pragma unroll
  for (int ki = 0; ki < 2; ++ki) {
    short8 vf0 = *(const short8*)&vb[(l15) * 64 + ki * 32 + quad * 8];
    short8 vf1 = *(const short8*)&vb[(16 + l15) * 64 + ki * 32 + quad * 8];
#pragma unroll
    for (int mi = 0; mi < 4; ++mi) {
      int q = mi * 16 + l15;
      short8 pa = *(const short8*)&Pw[q * 64 + (((ki * 4 + quad) ^ (q & 7)) << 3)];
      o[mi][0] = __builtin_amdgcn_mfma_f32_16x16x32_bf16(pa, vf0, o[mi][0], 0, 0, 0);
      o[mi][1] = __builtin_amdgcn_mfma_f32_16x16x32_bf16(pa, vf1, o[mi][1], 0, 0, 0);
    }
  }
#pragma unroll
  for (int mi = 0; mi < 4; ++mi)
#pragma unroll
    for (int ni = 0; ni < 2; ++ni)
#pragma unroll
      for (int r = 0; r < 4; ++r) {
        int t = mi * 16 + quad * 4 + r;
        ao[(size_t)(w * 64 + t) * 256 + head * 32 + ni * 16 + l15] = f2bf(o[mi][ni][r]);
      }
}

// ---- out-proj GEMM: out[131072,256] = AO @ wo^T + b, + merge/inv-roll scatter
__global__ __launch_bounds__(256) void oproj_kernel(
    const uint16_t* __restrict__ aob, const uint16_t* __restrict__ wo,
    const float* __restrict__ bout, float* __restrict__ out) {
  __shared__ uint16_t sm[8192];                  // 16 KB staging
  uint16_t* As = sm;
  uint16_t* Bs = sm + 4096;
  const int tid = threadIdx.x, lane = tid & 63, wv = tid >> 6;
  const int quad = lane >> 4, l15 = lane & 15;
  const int n0 = blockIdx.x * 128;
  const int m0 = blockIdx.y * 128;

  const int c0 = wv * 2, c1 = c0 + 1;
  const uint16_t* ap0 = aob + (size_t)(m0 + c0 * 16 + (lane >> 2)) * 256 + (lane & 3) * 8;
  const uint16_t* ap1 = aob + (size_t)(m0 + c1 * 16 + (lane >> 2)) * 256 + (lane & 3) * 8;
  const uint16_t* bp0 = wo + (size_t)(n0 + c0 * 16 + (lane >> 2)) * 256 + (lane & 3) * 8;
  const uint16_t* bp1 = wo + (size_t)(n0 + c1 * 16 + (lane >> 2)) * 256 + (lane & 3) * 8;

  const int wm = (wv & 1) * 64, wn = (wv >> 1) * 64;
  f32x4 zero = {0.f, 0.f, 0.f, 0.f};
  f32x4 acc[4][4];
#pragma unroll
  for (int mi = 0; mi < 4; ++mi)
#pragma unroll
    for (int ni = 0; ni < 4; ++ni) acc[mi][ni] = zero;

  for (int ks = 0; ks < 8; ++ks) {
    int k0 = ks * 32;
    g2lds16(ap0 + k0, &As[c0 * 512]);
    g2lds16(ap1 + k0, &As[c1 * 512]);
    g2lds16(bp0 + k0, &Bs[c0 * 512]);
    g2lds16(bp1 + k0, &Bs[c1 * 512]);
    __syncthreads();
    short8 af[4], bf[4];
#pragma unroll
    for (int mi = 0; mi < 4; ++mi)
      af[mi] = *(const short8*)&As[(wm + mi * 16 + l15) * 32 + quad * 8];
#pragma unroll
    for (int ni = 0; ni < 4; ++ni)
      bf[ni] = *(const short8*)&Bs[(wn + ni * 16 + l15) * 32 + quad * 8];
#pragma unroll
    for (int mi = 0; mi < 4; ++mi)
#pragma unroll
      for (int ni = 0; ni < 4; ++ni)
        acc[mi][ni] = __builtin_amdgcn_mfma_f32_16x16x32_bf16(af[mi], bf[ni], acc[mi][ni], 0, 0, 0);
    __syncthreads();
  }

  float bo4[4];
#pragma unroll
  for (int ni = 0; ni < 4; ++ni) bo4[ni] = bout[n0 + wn + ni * 16 + l15];
#pragma unroll
  for (int mi = 0; mi < 4; ++mi) {
    int mb = m0 + wm + mi * 16 + quad * 4;
    int w = mb >> 6, t0 = mb & 63;
    int b = w >> 6, wd = w & 63;
    int hw2 = wd >> 3, ww2 = wd & 7;
#pragma unroll
    for (int r = 0; r < 4; ++r) {
      int t = t0 + r;
      int h = hw2 * 8 + (t >> 3), xx = ww2 * 8 + (t & 7);
      int row = (((h + 4) & 63) << 6) | ((xx + 4) & 63);   // merge + inverse roll
      float* op = out + ((size_t)b * 4096 + row) * 256 + n0 + wn;
#pragma unroll
      for (int ni = 0; ni < 4; ++ni) op[ni * 16 + l15] = acc[mi][ni][r] + bo4[ni];
    }
  }
}

extern "C" void kernel_launch(void* const* d_in, const int* in_sizes, int n_in,
                              void* d_out, int out_size, void* d_ws, size_t ws_size,
                              hipStream_t stream) {
  const float* x = (const float*)d_in[0];
  const float* w_qkv = (const float*)d_in[1];
  const float* b_qkv = (const float*)d_in[2];
  const float* w_out = (const float*)d_in[3];
  const float* b_out = (const float*)d_in[4];
  const float* pos_enc = (const float*)d_in[5];
  float* out = (float*)d_out;

  uint8_t* ws = (uint8_t*)d_ws;
  uint16_t* xb  = (uint16_t*)(ws);                 // 67,108,864 B (reused as AO)
  uint16_t* wqb = (uint16_t*)(ws + 67108864);      //    393,216 B
  uint16_t* wob = (uint16_t*)(ws + 67502080);      //    131,072 B
  float*    bmt = (float*)   (ws + 67633152);      //  8,388,608 B
  uint16_t* qws = (uint16_t*)(ws + 76021760);      // 67,108,864 B
  uint16_t* kws = (uint16_t*)(ws + 143130624);     // 67,108,864 B
  uint16_t* vws = (uint16_t*)(ws + 210239488);     // 67,108,864 B -> 277,348,352 B
  uint16_t* aob = xb;                              // alias: xb dead after qkv

  cvtx_kernel<<<16384, 256, 0, stream>>>(x, xb);
  cvt_kernel<<<96, 256, 0, stream>>>(w_qkv, wqb, 196608);
  cvt_kernel<<<32, 256, 0, stream>>>(w_out, wob, 65536);
  bias_kernel<<<512, 256, 0, stream>>>(pos_enc, bmt);
  qkv_kernel<<<dim3(6, 1024), 256, 0, stream>>>(xb, wqb, b_qkv, qws, kws, vws);
  attn_kernel<<<4096, 256, 0, stream>>>(qws, kws, vws, bmt, aob);
  oproj_kernel<<<dim3(2, 1024), 256, 0, stream>>>(aob, wob, b_out, out);
}